// Round 3
// baseline (58.134 us; speedup 1.0000x reference)
//
#include <hip/hip_runtime.h>

// QuantumSelfAttention: closed-form collapse of the 10-qubit staircase circuit.
//
// Math (verified R1, absmax 3.9e-3 vs 2e-2 threshold):
//   q_0 = cos(x_0 + r_0)
//   q_j = cos(x_j + r_j) * (1 + sp2_{j-1} * (q_{j-1} - 1)),  sp2_i = sin^2(ent_i/2)
//   out_j = q_j      -- O(n) per sample instead of O(n * 2^n) statevector sim.
//
// R2 change: fully-coalesced global<->LDS staging (64 rows / 2560 B per block).
// R3 fix: cooperative-copy trip count was 160/64=2 (int division) -> last 32
// float4s per tile never copied (absmax 1.0). Ceil to 3; idx<n_f4 guard
// handles the partial iteration.

#define N_Q 10
#define ROWS_PER_BLOCK 64
#define TILE_FLOATS (ROWS_PER_BLOCK * N_Q)   // 640
#define TILE_F4     (TILE_FLOATS / 4)        // 160
#define COPY_ITERS  ((TILE_F4 + ROWS_PER_BLOCK - 1) / ROWS_PER_BLOCK)  // 3

__global__ __launch_bounds__(ROWS_PER_BLOCK) void qsa_kernel(
    const float* __restrict__ x,     // (T, 10)
    const float* __restrict__ rot,   // (10,)
    const float* __restrict__ ent,   // (9,)
    float* __restrict__ out,         // (T, 10)
    int T)
{
    __shared__ float tile[TILE_FLOATS];

    const int tid = threadIdx.x;
    const long long row0 = (long long)blockIdx.x * ROWS_PER_BLOCK;
    const long long base = row0 * N_Q;          // float offset of this block's tile

    // ---- cooperative coalesced load: global float4 -> LDS ----
    const float4* src4 = reinterpret_cast<const float4*>(x + base);
    float4* t4 = reinterpret_cast<float4*>(tile);
    const int n_f4 = (int)min((long long)TILE_F4,
                              ((long long)T * N_Q - base + 3) / 4);
#pragma unroll
    for (int i = 0; i < COPY_ITERS; ++i) {
        int idx = tid + i * ROWS_PER_BLOCK;
        if (idx < n_f4) t4[idx] = src4[idx];
    }
    __syncthreads();

    // ---- per-thread closed-form recursion (row = tid) ----
    float o[N_Q];
    const long long row = row0 + tid;
    if (row < T) {
        float sp2[N_Q - 1];
#pragma unroll
        for (int i = 0; i < N_Q - 1; ++i) {
            float s = __sinf(0.5f * ent[i]);   // broadcast load, L1-cached
            sp2[i] = s * s;
        }
        const float* xr = &tile[tid * N_Q];
        float q = __cosf(xr[0] + rot[0]);
        o[0] = q;
#pragma unroll
        for (int j = 1; j < N_Q; ++j) {
            float d = __cosf(xr[j] + rot[j]);
            q = d * fmaf(sp2[j - 1], q - 1.0f, 1.0f);
            o[j] = q;
        }
    }
    __syncthreads();   // tile reads done; safe to overwrite

    if (row < T) {
        float* orow = &tile[tid * N_Q];
#pragma unroll
        for (int j = 0; j < N_Q; ++j) orow[j] = o[j];
    }
    __syncthreads();

    // ---- cooperative coalesced store: LDS -> global float4 ----
    float4* dst4 = reinterpret_cast<float4*>(out + base);
#pragma unroll
    for (int i = 0; i < COPY_ITERS; ++i) {
        int idx = tid + i * ROWS_PER_BLOCK;
        if (idx < n_f4) dst4[idx] = t4[idx];
    }
}

extern "C" void kernel_launch(void* const* d_in, const int* in_sizes, int n_in,
                              void* d_out, int out_size, void* d_ws, size_t ws_size,
                              hipStream_t stream)
{
    const float* x   = (const float*)d_in[0];
    const float* rot = (const float*)d_in[1];
    const float* ent = (const float*)d_in[2];
    float* out = (float*)d_out;

    int T = in_sizes[0] / N_Q;  // 16 * 1024 = 16384
    int grid = (T + ROWS_PER_BLOCK - 1) / ROWS_PER_BLOCK;  // 256 blocks
    hipLaunchKernelGGL(qsa_kernel, dim3(grid), dim3(ROWS_PER_BLOCK), 0, stream,
                       x, rot, ent, out, T);
}